// Round 9
// baseline (181.938 us; speedup 1.0000x reference)
//
#include <hip/hip_runtime.h>
#include <stdint.h>

#define B_SZ 32
#define T_SZ 300
#define F_IN 3072
#define F_HID 410
#define F_OUT 10
#define M_SZ (B_SZ * T_SZ)              // 9600
#define N_PAD 448                       // a1 row stride = gemm1 N (7 x 64)
#define KW (F_IN / 32)                  // 96 bit-words per spike row
#define TOTAL_ELEMS (B_SZ * T_SZ * F_IN)
#define N_WORDS (TOTAL_ELEMS / 32)      // 921600
#define A2_STRIDE 16
#define NCHUNK 10
#define CLEN 30
#define NKB (F_IN / 256)                // 12 K-blocks of 256
#define MT_CNT (M_SZ / 64)              // 150 m-tiles
#define W1_BLOCKS 672                   // 448*3072/8/256
#define RNG_BLOCKS 14400                // 921600*4/256 (4 threads/word, 8 bits each)

// f32(exp(f32(-0.1))) — PSP decay, matches XLA's correctly-rounded exp
#define DECAY 0.90483741803595957f
#define THETA 10.0f

typedef __attribute__((ext_vector_type(8))) int i32x8;
typedef __attribute__((ext_vector_type(16))) float f32x16;

#define ROTL(x, r) __builtin_amdgcn_alignbit((x), (x), 32u - (r))

// JAX threefry2x32, key = (0, 42)
__device__ __forceinline__ void threefry2x32(uint32_t& x0, uint32_t& x1) {
  const uint32_t ks0 = 0u;
  const uint32_t ks1 = 42u;
  const uint32_t ks2 = 0x1BD11BDAu ^ 0u ^ 42u;
  x0 += ks0; x1 += ks1;
#define TF_ROUND(r) { x0 += x1; x1 = ROTL(x1, (r)); x1 ^= x0; }
  TF_ROUND(13) TF_ROUND(15) TF_ROUND(26) TF_ROUND(6)
  x0 += ks1; x1 += ks2 + 1u;
  TF_ROUND(17) TF_ROUND(29) TF_ROUND(16) TF_ROUND(24)
  x0 += ks2; x1 += ks0 + 2u;
  TF_ROUND(13) TF_ROUND(15) TF_ROUND(26) TF_ROUND(6)
  x0 += ks0; x1 += ks1 + 3u;
  TF_ROUND(17) TF_ROUND(29) TF_ROUND(16) TF_ROUND(24)
  x0 += ks1; x1 += ks2 + 4u;
  TF_ROUND(13) TF_ROUND(15) TF_ROUND(26) TF_ROUND(6)
  x0 += ks2; x1 += ks0 + 5u;
#undef TF_ROUND
}

// async global->LDS, 16 B per lane; LDS dest = wave-uniform base + lane*16
__device__ __forceinline__ void gld16(const void* g, void* l) {
  __builtin_amdgcn_global_load_lds(
      (const __attribute__((address_space(1))) uint32_t*)g,
      (__attribute__((address_space(3))) uint32_t*)l, 16, 0, 0);
}

// Merged prep.
// Blocks [0, 672): W1 fp32 -> e4m3, stored PRE-SWIZZLED in the gemm1 LDS
//   image layout (rows >= 410 zeroed) so global_load_lds DMA produces a
//   conflict-free LDS tile directly.
// Blocks [672, 672+14400): partitionable threefry rate-encode. 4 threads per
//   32-bit word, 8 counters each -> one byte (consecutive byte stores =
//   coalesced). Thresholds as INTEGERS: u < p  <=>  (bits>>9) < ceil(p*2^23)
//   (exact: *2^23 is an exponent shift; m = u*2^23 is an integer). 8 int
//   thresholds fit in regs -> loop fully unrolls (R8: VGPR=24 forced a rolled
//   loop with ~1.7x VALU overhead).
__global__ __launch_bounds__(256) void prep(const float* __restrict__ inp,
                                            const float* __restrict__ W1,
                                            uint8_t* __restrict__ W1s,
                                            uint32_t* __restrict__ sbitsT) {
  if (blockIdx.x < W1_BLOCKS) {
    int idx = blockIdx.x * 256 + threadIdx.x;
    int g = idx * 8;
    int n = g / F_IN;
    int k = g - n * F_IN;
    uint32_t d0 = 0u, d1 = 0u;
    if (n < F_HID) {
      const float* s = W1 + (size_t)n * F_IN + k;
      float4 v0 = ((const float4*)s)[0];
      float4 v1 = ((const float4*)s)[1];
      int t0 = __builtin_amdgcn_cvt_pk_fp8_f32(v0.x, v0.y, 0, false);
      t0 = __builtin_amdgcn_cvt_pk_fp8_f32(v0.z, v0.w, t0, true);
      int t1 = __builtin_amdgcn_cvt_pk_fp8_f32(v1.x, v1.y, 0, false);
      t1 = __builtin_amdgcn_cvt_pk_fp8_f32(v1.z, v1.w, t1, true);
      d0 = (uint32_t)t0; d1 = (uint32_t)t1;
    }
    int nt = n >> 6, r = n & 63;
    int kb = k >> 8, c = (k >> 4) & 15, half = (k >> 3) & 1;
    size_t dst = ((((size_t)nt * NKB + kb) * 64 + r) * 16 + (c ^ (r & 15))) * 16 + half * 8;
    *(uint2*)(W1s + dst) = make_uint2(d0, d1);
  } else {
    uint32_t idx = (blockIdx.x - W1_BLOCKS) * 256u + threadIdx.x;  // [0, 3686400)
    uint32_t q = idx & 3u;          // byte within word
    uint32_t j = idx >> 2;          // word index [0, 921600)
    uint32_t r = j & 63u;
    uint32_t t1 = j >> 6;
    uint32_t wi = t1 & 7u;
    uint32_t t2 = t1 >> 3;          // (mt*12 + kb) in [0, 1800)
    uint32_t kb = t2 % (uint32_t)NKB;
    uint32_t mt = t2 / (uint32_t)NKB;
    uint32_t m = mt * 64u + r;      // GEMM row = b*300 + t
    uint32_t b = m / (uint32_t)T_SZ;
    uint32_t f = (kb * 8u + wi) * 32u + q * 8u;
    const float* p = inp + b * F_IN + f;
    uint32_t T[8];
#pragma unroll
    for (int qq = 0; qq < 2; ++qq) {
      float4 v = ((const float4*)p)[qq];
      T[qq * 4 + 0] = (uint32_t)ceilf(v.x * 8388608.0f);
      T[qq * 4 + 1] = (uint32_t)ceilf(v.y * 8388608.0f);
      T[qq * 4 + 2] = (uint32_t)ceilf(v.z * 8388608.0f);
      T[qq * 4 + 3] = (uint32_t)ceilf(v.w * 8388608.0f);
    }
    uint32_t base = m * (uint32_t)F_IN + f;   // flat counter index of bit 0
    uint32_t w = 0u;
#pragma unroll
    for (int jj = 7; jj >= 0; --jj) {         // MSB-first: w = 2w + bit
      uint32_t x0 = 0u, x1 = base + (uint32_t)jj;
      threefry2x32(x0, x1);
      uint32_t mm = (x0 ^ x1) >> 9;
      w = w + w + (mm < T[jj] ? 1u : 0u);
    }
    ((uint8_t*)sbitsT)[idx] = w;   // byte q of word j: bits [8q, 8q+8)
  }
}

// a1[m][n] = sum_k spike(m,k)*W1[n][k], MX-fp8 MFMA 32x32x64 (scales=127=2^0).
// BM=64, BN=64, BK=256, grid 150x7=1050, 256 thr = 4 waves (2x2 of 32x32).
// ALL staging via global_load_lds (no staging VGPRs -> no spill). W1s is
// pre-swizzled in memory; sbitsT pre-transposed. A bits expanded to fp8 at
// frag read (mul-spread). acc = 16 AGPR.
__global__ __launch_bounds__(256) void gemm1(const uint32_t* __restrict__ sbitsT,
                                             const uint8_t* __restrict__ W1s,
                                             float* __restrict__ a1) {
  __shared__ uint32_t sAT[8 * 64];   // 2 KB: [word][row]
  __shared__ uint8_t sB[64 * 256];   // 16 KB: swizzled LDS image

  const int tid = threadIdx.x;
  const int mtile = blockIdx.x;
  const int nt = blockIdx.y;
  const int m0 = mtile * 64;
  const int n0 = nt * 64;
  const int wv = tid >> 6, lane = tid & 63;
  const int wm = (wv & 1) * 32, wn = (wv >> 1) * 32;
  const int l31 = lane & 31, lh = lane >> 5;

  const uint8_t* gB0 = W1s + (size_t)nt * NKB * 16384;
  const uint8_t* gA0 = (const uint8_t*)sbitsT + (size_t)mtile * NKB * 2048;

  f32x16 acc;
#pragma unroll
  for (int e = 0; e < 16; ++e) acc[e] = 0.0f;

  for (int kb = 0; kb < NKB; ++kb) {
    const uint8_t* gB = gB0 + (size_t)kb * 16384;
#pragma unroll
    for (int q = 0; q < 4; ++q)
      gld16(gB + (wv * 4 + q) * 1024 + lane * 16, &sB[(wv * 4 + q) * 1024]);
    if (wv < 2)
      gld16(gA0 + (size_t)kb * 2048 + wv * 1024 + lane * 16,
            (uint8_t*)sAT + wv * 1024);
    __syncthreads();   // vmcnt drain + visibility
#pragma unroll
    for (int sub = 0; sub < 4; ++sub) {
      // B frag: B[n = wn+l31][k = sub*64 + lh*32 + 0..31]
      int row = wn + l31;
      int cb = sub * 4 + lh * 2;
      uint4 u0 = *(uint4*)&sB[row * 256 + (((cb + 0) ^ (row & 15)) << 4)];
      uint4 u1 = *(uint4*)&sB[row * 256 + (((cb + 1) ^ (row & 15)) << 4)];
      i32x8 bfr;
      bfr[0] = u0.x; bfr[1] = u0.y; bfr[2] = u0.z; bfr[3] = u0.w;
      bfr[4] = u1.x; bfr[5] = u1.y; bfr[6] = u1.z; bfr[7] = u1.w;
      // A frag: A[m = wm+l31][same k], expanded bits -> fp8(1.0)=0x38
      uint32_t w = sAT[(sub * 2 + lh) * 64 + wm + l31];
      i32x8 afr;
#pragma unroll
      for (int j = 0; j < 8; ++j) {
        uint32_t n = (w >> (4 * j)) & 15u;
        afr[j] = (int)(((n * 0x204081u) & 0x01010101u) * 0x38u);
      }
      acc = __builtin_amdgcn_mfma_scale_f32_32x32x64_f8f6f4(
          afr, bfr, acc, 0, 0, 0, 127, 0, 127);
    }
    __syncthreads();   // LDS free before next kb's DMA
  }
  // epilogue: C/D 32x32: col = lane&31, row = (reg&3) + 8*(reg>>2) + 4*(lane>>5)
  int col = n0 + wn + l31;
#pragma unroll
  for (int rg = 0; rg < 16; ++rg) {
    int row = m0 + wm + (rg & 3) + 8 * (rg >> 2) + 4 * lh;
    a1[(size_t)row * N_PAD + col] = acc[rg];
  }
}

// PSP phase A: per-(b,chunk,o) partial scan from 0; partials overwrite a1;
// raw chunk finals pf -> fin[b][c][o].
__global__ __launch_bounds__(256) void psp1_partial(float* __restrict__ a1,
                                                    float* __restrict__ fin) {
  int idx = blockIdx.x * 256 + threadIdx.x;   // 32*10*448 = 143360
  if (idx >= B_SZ * NCHUNK * N_PAD) return;
  int o = idx % N_PAD;
  int bc = idx / N_PAD;
  int c = bc % NCHUNK;
  int b = bc / NCHUNK;
  float* p = a1 + ((size_t)(b * T_SZ + c * CLEN)) * N_PAD + o;
  float u = 0.0f;
#pragma unroll
  for (int i = 0; i < CLEN; ++i) {
    u = __fadd_rn(__fmul_rn(DECAY, u), p[(size_t)i * N_PAD]);
    p[(size_t)i * N_PAD] = u;
  }
  fin[(size_t)bc * N_PAD + o] = u;
}

// Fused chunk-combine + PSP apply + layer-2 GEMM. One wave per (b,t).
__global__ __launch_bounds__(256) void apply_gemm2(const float* __restrict__ a1,
                                                   const float* __restrict__ fin,
                                                   const float* __restrict__ W2,
                                                   float* __restrict__ a2) {
  __shared__ float sW2[F_OUT * F_HID];   // 16.4 KB
  for (int i = threadIdx.x; i < F_OUT * F_HID; i += 256) sW2[i] = W2[i];
  __syncthreads();
  int m = blockIdx.x * 4 + (threadIdx.x >> 6);
  int lane = threadIdx.x & 63;
  int b = m / T_SZ, t = m % T_SZ;
  int c = t / CLEN, tl = t % CLEN;
  float d30 = 1.0f;
#pragma unroll
  for (int i = 0; i < CLEN; ++i) d30 *= DECAY;
  float dp = DECAY;
  for (int i = 0; i < tl; ++i) dp *= DECAY;   // decay^(tl+1), wave-uniform
  float p[F_OUT];
#pragma unroll
  for (int o = 0; o < F_OUT; ++o) p[o] = 0.0f;
#pragma unroll
  for (int j = 0; j < 7; ++j) {
    int hh = lane + j * 64;
    float u = a1[(size_t)m * N_PAD + hh];
    if (c > 0) {
      float F = 0.0f;
      const float* f = fin + (size_t)b * NCHUNK * N_PAD + hh;
      for (int cc = 0; cc < c; ++cc)          // wave-uniform trip count
        F = f[(size_t)cc * N_PAD] + d30 * F;
      u = __fadd_rn(u, __fmul_rn(dp, F));
    }
    bool valid = hh < F_HID;
    float s = (u >= THETA && valid) ? 1.0f : 0.0f;
    int hcl = valid ? hh : 0;
#pragma unroll
    for (int o = 0; o < F_OUT; ++o) p[o] = fmaf(s, sW2[o * F_HID + hcl], p[o]);
  }
#pragma unroll
  for (int o = 0; o < F_OUT; ++o)
#pragma unroll
    for (int s = 1; s < 64; s <<= 1) p[o] += __shfl_xor(p[o], s, 64);
  if (lane < F_OUT) a2[(size_t)m * A2_STRIDE + lane] = p[lane];
}

// Layer-2 PSP, chunked, one block per batch; lanes (o,c) in [10x10].
__global__ __launch_bounds__(128) void psp2(const float* __restrict__ a2,
                                            float* __restrict__ out) {
  __shared__ float chf[NCHUNK][F_OUT];
  __shared__ float seed[NCHUNK][F_OUT];
  int b = blockIdx.x;
  int tid = threadIdx.x;
  int o = tid / NCHUNK, c = tid % NCHUNK;
  const float* p = a2 + ((size_t)(b * T_SZ + c * CLEN)) * A2_STRIDE + o;
  float v[CLEN];
  float pa[CLEN];
  if (tid < F_OUT * NCHUNK) {
#pragma unroll
    for (int i = 0; i < CLEN; ++i) v[i] = p[(size_t)i * A2_STRIDE];
    float u = 0.0f;
#pragma unroll
    for (int i = 0; i < CLEN; ++i) {
      u = __fadd_rn(__fmul_rn(DECAY, u), v[i]);
      pa[i] = u;
    }
    chf[c][o] = u;
  }
  __syncthreads();
  if (tid < F_OUT) {
    float d30 = 1.0f;
#pragma unroll
    for (int i = 0; i < CLEN; ++i) d30 *= DECAY;
    float F = 0.0f;
    for (int cc = 0; cc < NCHUNK; ++cc) {
      F = chf[cc][tid] + d30 * F;
      seed[cc][tid] = F;
    }
  }
  __syncthreads();
  if (tid < F_OUT * NCHUNK) {
    float F = (c == 0) ? 0.0f : seed[c - 1][o];
    float dp = DECAY;
    float* q = out + (size_t)b * F_OUT * T_SZ + (size_t)o * T_SZ + c * CLEN;
#pragma unroll
    for (int i = 0; i < CLEN; ++i) {
      float u = (c == 0) ? pa[i] : __fadd_rn(pa[i], __fmul_rn(dp, F));
      q[i] = (u >= THETA) ? 1.0f : 0.0f;
      dp *= DECAY;
    }
  }
}

extern "C" void kernel_launch(void* const* d_in, const int* in_sizes, int n_in,
                              void* d_out, int out_size, void* d_ws, size_t ws_size,
                              hipStream_t stream) {
  const float* inp = (const float*)d_in[0];  // [32,3,32,32]
  const float* W1  = (const float*)d_in[1];  // [410,3072]
  const float* W2  = (const float*)d_in[2];  // [10,410]
  float* out = (float*)d_out;                // [32,10,300]
  char* ws = (char*)d_ws;
  // ws: W1s 1376256 | sbitsT 3686400 | a1 17203200 | fin 573440 | a2 614400
  uint8_t* W1s = (uint8_t*)(ws);
  uint32_t* sbitsT = (uint32_t*)(ws + 1376256);
  float* a1 = (float*)(ws + 1376256 + 3686400);
  float* fin = a1 + (size_t)M_SZ * N_PAD;
  float* a2 = fin + (size_t)B_SZ * NCHUNK * N_PAD;

  prep<<<dim3(W1_BLOCKS + RNG_BLOCKS), dim3(256), 0, stream>>>(inp, W1, W1s, sbitsT);
  gemm1<<<dim3(MT_CNT, N_PAD / 64), dim3(256), 0, stream>>>(sbitsT, W1s, a1);
  psp1_partial<<<dim3((B_SZ * NCHUNK * N_PAD) / 256), dim3(256), 0, stream>>>(a1, fin);
  apply_gemm2<<<dim3(M_SZ / 4), dim3(256), 0, stream>>>(a1, fin, W2, a2);
  psp2<<<dim3(B_SZ), dim3(128), 0, stream>>>(a2, out);
}

// Round 10
// 173.572 us; speedup vs baseline: 1.0482x; 1.0482x over previous
//
#include <hip/hip_runtime.h>
#include <stdint.h>

#define B_SZ 32
#define T_SZ 300
#define F_IN 3072
#define F_HID 410
#define F_OUT 10
#define M_SZ (B_SZ * T_SZ)              // 9600
#define N_PAD 448                       // a1 row stride = gemm1 N (7 x 64)
#define KW (F_IN / 32)                  // 96 bit-words per spike row
#define TOTAL_ELEMS (B_SZ * T_SZ * F_IN)
#define N_WORDS (TOTAL_ELEMS / 32)      // 921600
#define A2_STRIDE 16
#define NCHUNK 10
#define CLEN 30
#define NKB (F_IN / 256)                // 12 K-blocks of 256
#define MT_CNT (M_SZ / 64)              // 150 m-tiles
#define W1_BLOCKS 672                   // 448*3072/8/256
#define RNG_BLOCKS 14400                // 921600*4/256 (4 threads/word, 8 bits each)

// f32(exp(f32(-0.1))) — PSP decay, matches XLA's correctly-rounded exp
#define DECAY 0.90483741803595957f
#define THETA 10.0f
#define KS2 (0x1BD11BDAu ^ 42u)

typedef __attribute__((ext_vector_type(8))) int i32x8;
typedef __attribute__((ext_vector_type(16))) float f32x16;

// FORCED single-instruction rotate-left: v_alignbit_b32 x,x,x,(32-r) is
// rotr(32-r) = rotl(r). Busy-cycle math (R8/R9: ~133 VALU/bit vs 75 ideal)
// says the generic (x<<r)|(x>>(32-r)) AND the alignbit builtin both lowered
// to 3-op expansions; inline asm pins the 1-op form.
#define TF_R(r) { x0 += x1; \
  asm("v_alignbit_b32 %0, %1, %1, %2" : "=v"(x1) : "v"(x1), "n"(32 - (r))); \
  x1 ^= x0; }

// JAX threefry2x32, key=(0,42), ctr=(0, x1i-42). x0 key-add is 0 (elided);
// x1 key-add folded into caller's x1i = base + 42 + jj. Returns o0 ^ o1.
__device__ __forceinline__ uint32_t tf_bits(uint32_t x1i) {
  uint32_t x0 = 0u, x1 = x1i;
  TF_R(13) TF_R(15) TF_R(26) TF_R(6)
  x0 += 42u; x1 += KS2 + 1u;
  TF_R(17) TF_R(29) TF_R(16) TF_R(24)
  x0 += KS2; x1 += 2u;
  TF_R(13) TF_R(15) TF_R(26) TF_R(6)
  x1 += 42u + 3u;
  TF_R(17) TF_R(29) TF_R(16) TF_R(24)
  x0 += 42u; x1 += KS2 + 4u;
  TF_R(13) TF_R(15) TF_R(26) TF_R(6)
  x0 += KS2; x1 += 5u;
  return x0 ^ x1;
}

// async global->LDS, 16 B per lane; LDS dest = wave-uniform base + lane*16
__device__ __forceinline__ void gld16(const void* g, void* l) {
  __builtin_amdgcn_global_load_lds(
      (const __attribute__((address_space(1))) uint32_t*)g,
      (__attribute__((address_space(3))) uint32_t*)l, 16, 0, 0);
}

// Merged prep.
// Blocks [0, 672): W1 fp32 -> e4m3, PRE-SWIZZLED into the gemm1 LDS image
//   (rows >= 410 zeroed) so global_load_lds DMA yields conflict-free tiles.
// Blocks [672, 672+14400): partitionable threefry rate-encode, 4 threads per
//   32-bit word (one byte each, coalesced byte stores). Integer thresholds:
//   u < p  <=>  (bits>>9) < ceil(p*2^23)  (exact). Straight-line 8x threefry
//   with named threshold regs.
__global__ __launch_bounds__(256) void prep(const float* __restrict__ inp,
                                            const float* __restrict__ W1,
                                            uint8_t* __restrict__ W1s,
                                            uint32_t* __restrict__ sbitsT) {
  if (blockIdx.x < W1_BLOCKS) {
    int idx = blockIdx.x * 256 + threadIdx.x;
    int g = idx * 8;
    int n = g / F_IN;
    int k = g - n * F_IN;
    uint32_t d0 = 0u, d1 = 0u;
    if (n < F_HID) {
      const float* s = W1 + (size_t)n * F_IN + k;
      float4 v0 = ((const float4*)s)[0];
      float4 v1 = ((const float4*)s)[1];
      int t0 = __builtin_amdgcn_cvt_pk_fp8_f32(v0.x, v0.y, 0, false);
      t0 = __builtin_amdgcn_cvt_pk_fp8_f32(v0.z, v0.w, t0, true);
      int t1 = __builtin_amdgcn_cvt_pk_fp8_f32(v1.x, v1.y, 0, false);
      t1 = __builtin_amdgcn_cvt_pk_fp8_f32(v1.z, v1.w, t1, true);
      d0 = (uint32_t)t0; d1 = (uint32_t)t1;
    }
    int nt = n >> 6, r = n & 63;
    int kb = k >> 8, c = (k >> 4) & 15, half = (k >> 3) & 1;
    size_t dst = ((((size_t)nt * NKB + kb) * 64 + r) * 16 + (c ^ (r & 15))) * 16 + half * 8;
    *(uint2*)(W1s + dst) = make_uint2(d0, d1);
  } else {
    uint32_t idx = (blockIdx.x - W1_BLOCKS) * 256u + threadIdx.x;  // [0, 3686400)
    uint32_t q = idx & 3u;          // byte within word
    uint32_t j = idx >> 2;          // word index [0, 921600)
    uint32_t r = j & 63u;
    uint32_t t1 = j >> 6;
    uint32_t wi = t1 & 7u;
    uint32_t t2 = t1 >> 3;          // (mt*12 + kb) in [0, 1800)
    uint32_t kb = t2 % (uint32_t)NKB;
    uint32_t mt = t2 / (uint32_t)NKB;
    uint32_t m = mt * 64u + r;      // GEMM row = b*300 + t
    uint32_t b = m / (uint32_t)T_SZ;
    uint32_t f = (kb * 8u + wi) * 32u + q * 8u;
    const float* p = inp + b * F_IN + f;
    float4 va = ((const float4*)p)[0];
    float4 vb = ((const float4*)p)[1];
    uint32_t T0 = (uint32_t)ceilf(va.x * 8388608.0f);
    uint32_t T1 = (uint32_t)ceilf(va.y * 8388608.0f);
    uint32_t T2 = (uint32_t)ceilf(va.z * 8388608.0f);
    uint32_t T3 = (uint32_t)ceilf(va.w * 8388608.0f);
    uint32_t T4 = (uint32_t)ceilf(vb.x * 8388608.0f);
    uint32_t T5 = (uint32_t)ceilf(vb.y * 8388608.0f);
    uint32_t T6 = (uint32_t)ceilf(vb.z * 8388608.0f);
    uint32_t T7 = (uint32_t)ceilf(vb.w * 8388608.0f);
    uint32_t b42 = m * (uint32_t)F_IN + f + 42u;   // counter base + key lo
    uint32_t w = 0u;
#define GEN(jj, Tn) { uint32_t bits = tf_bits(b42 + (jj)); \
  w |= ((bits >> 9) < (Tn)) ? (1u << (jj)) : 0u; }
    GEN(0, T0) GEN(1, T1) GEN(2, T2) GEN(3, T3)
    GEN(4, T4) GEN(5, T5) GEN(6, T6) GEN(7, T7)
#undef GEN
    ((uint8_t*)sbitsT)[idx] = (uint8_t)w;   // byte q of word j: bits [8q, 8q+8)
  }
}

// a1[m][n] = sum_k spike(m,k)*W1[n][k], MX-fp8 MFMA 32x32x64 (scales=127=2^0).
// BM=64, BN=64, BK=256, grid 150x7=1050, 256 thr = 4 waves (2x2 of 32x32).
// ALL staging via global_load_lds (no staging VGPRs -> no spill). W1s is
// pre-swizzled in memory; sbitsT pre-transposed. A bits expanded to fp8 at
// frag read (mul-spread). acc = 16 AGPR.
__global__ __launch_bounds__(256) void gemm1(const uint32_t* __restrict__ sbitsT,
                                             const uint8_t* __restrict__ W1s,
                                             float* __restrict__ a1) {
  __shared__ uint32_t sAT[8 * 64];   // 2 KB: [word][row]
  __shared__ uint8_t sB[64 * 256];   // 16 KB: swizzled LDS image

  const int tid = threadIdx.x;
  const int mtile = blockIdx.x;
  const int nt = blockIdx.y;
  const int m0 = mtile * 64;
  const int n0 = nt * 64;
  const int wv = tid >> 6, lane = tid & 63;
  const int wm = (wv & 1) * 32, wn = (wv >> 1) * 32;
  const int l31 = lane & 31, lh = lane >> 5;

  const uint8_t* gB0 = W1s + (size_t)nt * NKB * 16384;
  const uint8_t* gA0 = (const uint8_t*)sbitsT + (size_t)mtile * NKB * 2048;

  f32x16 acc;
#pragma unroll
  for (int e = 0; e < 16; ++e) acc[e] = 0.0f;

  for (int kb = 0; kb < NKB; ++kb) {
    const uint8_t* gB = gB0 + (size_t)kb * 16384;
#pragma unroll
    for (int q = 0; q < 4; ++q)
      gld16(gB + (wv * 4 + q) * 1024 + lane * 16, &sB[(wv * 4 + q) * 1024]);
    if (wv < 2)
      gld16(gA0 + (size_t)kb * 2048 + wv * 1024 + lane * 16,
            (uint8_t*)sAT + wv * 1024);
    __syncthreads();   // vmcnt drain + visibility
#pragma unroll
    for (int sub = 0; sub < 4; ++sub) {
      // B frag: B[n = wn+l31][k = sub*64 + lh*32 + 0..31]
      int row = wn + l31;
      int cb = sub * 4 + lh * 2;
      uint4 u0 = *(uint4*)&sB[row * 256 + (((cb + 0) ^ (row & 15)) << 4)];
      uint4 u1 = *(uint4*)&sB[row * 256 + (((cb + 1) ^ (row & 15)) << 4)];
      i32x8 bfr;
      bfr[0] = u0.x; bfr[1] = u0.y; bfr[2] = u0.z; bfr[3] = u0.w;
      bfr[4] = u1.x; bfr[5] = u1.y; bfr[6] = u1.z; bfr[7] = u1.w;
      // A frag: A[m = wm+l31][same k], expanded bits -> fp8(1.0)=0x38
      uint32_t w = sAT[(sub * 2 + lh) * 64 + wm + l31];
      i32x8 afr;
#pragma unroll
      for (int j = 0; j < 8; ++j) {
        uint32_t n = (w >> (4 * j)) & 15u;
        afr[j] = (int)(((n * 0x204081u) & 0x01010101u) * 0x38u);
      }
      acc = __builtin_amdgcn_mfma_scale_f32_32x32x64_f8f6f4(
          afr, bfr, acc, 0, 0, 0, 127, 0, 127);
    }
    __syncthreads();   // LDS free before next kb's DMA
  }
  // epilogue: C/D 32x32: col = lane&31, row = (reg&3) + 8*(reg>>2) + 4*(lane>>5)
  int col = n0 + wn + l31;
#pragma unroll
  for (int rg = 0; rg < 16; ++rg) {
    int row = m0 + wm + (rg & 3) + 8 * (rg >> 2) + 4 * lh;
    a1[(size_t)row * N_PAD + col] = acc[rg];
  }
}

// PSP phase A: per-(b,chunk,o) partial scan from 0; partials overwrite a1;
// raw chunk finals pf -> fin[b][c][o].
__global__ __launch_bounds__(256) void psp1_partial(float* __restrict__ a1,
                                                    float* __restrict__ fin) {
  int idx = blockIdx.x * 256 + threadIdx.x;   // 32*10*448 = 143360
  if (idx >= B_SZ * NCHUNK * N_PAD) return;
  int o = idx % N_PAD;
  int bc = idx / N_PAD;
  int c = bc % NCHUNK;
  int b = bc / NCHUNK;
  float* p = a1 + ((size_t)(b * T_SZ + c * CLEN)) * N_PAD + o;
  float u = 0.0f;
#pragma unroll
  for (int i = 0; i < CLEN; ++i) {
    u = __fadd_rn(__fmul_rn(DECAY, u), p[(size_t)i * N_PAD]);
    p[(size_t)i * N_PAD] = u;
  }
  fin[(size_t)bc * N_PAD + o] = u;
}

// Fused chunk-combine + PSP apply + layer-2 GEMM. One wave per (b,t).
__global__ __launch_bounds__(256) void apply_gemm2(const float* __restrict__ a1,
                                                   const float* __restrict__ fin,
                                                   const float* __restrict__ W2,
                                                   float* __restrict__ a2) {
  __shared__ float sW2[F_OUT * F_HID];   // 16.4 KB
  for (int i = threadIdx.x; i < F_OUT * F_HID; i += 256) sW2[i] = W2[i];
  __syncthreads();
  int m = blockIdx.x * 4 + (threadIdx.x >> 6);
  int lane = threadIdx.x & 63;
  int b = m / T_SZ, t = m % T_SZ;
  int c = t / CLEN, tl = t % CLEN;
  float d30 = 1.0f;
#pragma unroll
  for (int i = 0; i < CLEN; ++i) d30 *= DECAY;
  float dp = DECAY;
  for (int i = 0; i < tl; ++i) dp *= DECAY;   // decay^(tl+1), wave-uniform
  float p[F_OUT];
#pragma unroll
  for (int o = 0; o < F_OUT; ++o) p[o] = 0.0f;
#pragma unroll
  for (int j = 0; j < 7; ++j) {
    int hh = lane + j * 64;
    float u = a1[(size_t)m * N_PAD + hh];
    if (c > 0) {
      float F = 0.0f;
      const float* f = fin + (size_t)b * NCHUNK * N_PAD + hh;
      for (int cc = 0; cc < c; ++cc)          // wave-uniform trip count
        F = f[(size_t)cc * N_PAD] + d30 * F;
      u = __fadd_rn(u, __fmul_rn(dp, F));
    }
    bool valid = hh < F_HID;
    float s = (u >= THETA && valid) ? 1.0f : 0.0f;
    int hcl = valid ? hh : 0;
#pragma unroll
    for (int o = 0; o < F_OUT; ++o) p[o] = fmaf(s, sW2[o * F_HID + hcl], p[o]);
  }
#pragma unroll
  for (int o = 0; o < F_OUT; ++o)
#pragma unroll
    for (int s = 1; s < 64; s <<= 1) p[o] += __shfl_xor(p[o], s, 64);
  if (lane < F_OUT) a2[(size_t)m * A2_STRIDE + lane] = p[lane];
}

// Layer-2 PSP, chunked, one block per batch; lanes (o,c) in [10x10].
__global__ __launch_bounds__(128) void psp2(const float* __restrict__ a2,
                                            float* __restrict__ out) {
  __shared__ float chf[NCHUNK][F_OUT];
  __shared__ float seed[NCHUNK][F_OUT];
  int b = blockIdx.x;
  int tid = threadIdx.x;
  int o = tid / NCHUNK, c = tid % NCHUNK;
  const float* p = a2 + ((size_t)(b * T_SZ + c * CLEN)) * A2_STRIDE + o;
  float v[CLEN];
  float pa[CLEN];
  if (tid < F_OUT * NCHUNK) {
#pragma unroll
    for (int i = 0; i < CLEN; ++i) v[i] = p[(size_t)i * A2_STRIDE];
    float u = 0.0f;
#pragma unroll
    for (int i = 0; i < CLEN; ++i) {
      u = __fadd_rn(__fmul_rn(DECAY, u), v[i]);
      pa[i] = u;
    }
    chf[c][o] = u;
  }
  __syncthreads();
  if (tid < F_OUT) {
    float d30 = 1.0f;
#pragma unroll
    for (int i = 0; i < CLEN; ++i) d30 *= DECAY;
    float F = 0.0f;
    for (int cc = 0; cc < NCHUNK; ++cc) {
      F = chf[cc][tid] + d30 * F;
      seed[cc][tid] = F;
    }
  }
  __syncthreads();
  if (tid < F_OUT * NCHUNK) {
    float F = (c == 0) ? 0.0f : seed[c - 1][o];
    float dp = DECAY;
    float* q = out + (size_t)b * F_OUT * T_SZ + (size_t)o * T_SZ + c * CLEN;
#pragma unroll
    for (int i = 0; i < CLEN; ++i) {
      float u = (c == 0) ? pa[i] : __fadd_rn(pa[i], __fmul_rn(dp, F));
      q[i] = (u >= THETA) ? 1.0f : 0.0f;
      dp *= DECAY;
    }
  }
}

extern "C" void kernel_launch(void* const* d_in, const int* in_sizes, int n_in,
                              void* d_out, int out_size, void* d_ws, size_t ws_size,
                              hipStream_t stream) {
  const float* inp = (const float*)d_in[0];  // [32,3,32,32]
  const float* W1  = (const float*)d_in[1];  // [410,3072]
  const float* W2  = (const float*)d_in[2];  // [10,410]
  float* out = (float*)d_out;                // [32,10,300]
  char* ws = (char*)d_ws;
  // ws: W1s 1376256 | sbitsT 3686400 | a1 17203200 | fin 573440 | a2 614400
  uint8_t* W1s = (uint8_t*)(ws);
  uint32_t* sbitsT = (uint32_t*)(ws + 1376256);
  float* a1 = (float*)(ws + 1376256 + 3686400);
  float* fin = a1 + (size_t)M_SZ * N_PAD;
  float* a2 = fin + (size_t)B_SZ * NCHUNK * N_PAD;

  prep<<<dim3(W1_BLOCKS + RNG_BLOCKS), dim3(256), 0, stream>>>(inp, W1, W1s, sbitsT);
  gemm1<<<dim3(MT_CNT, N_PAD / 64), dim3(256), 0, stream>>>(sbitsT, W1s, a1);
  psp1_partial<<<dim3((B_SZ * NCHUNK * N_PAD) / 256), dim3(256), 0, stream>>>(a1, fin);
  apply_gemm2<<<dim3(M_SZ / 4), dim3(256), 0, stream>>>(a1, fin, W2, a2);
  psp2<<<dim3(B_SZ), dim3(128), 0, stream>>>(a2, out);
}